// Round 11
// baseline (249.803 us; speedup 1.0000x reference)
//
#include <hip/hip_runtime.h>
#include <hip/hip_bf16.h>
#include <cstdint>

typedef __bf16 bf16_t;
typedef __attribute__((ext_vector_type(8)))  __bf16 bf16x8;
typedef __attribute__((ext_vector_type(4)))  float  f32x4;
typedef __attribute__((ext_vector_type(16))) float  f32x16;

#define AS1 __attribute__((address_space(1)))
#define AS3 __attribute__((address_space(3)))
#define DEV __device__ __forceinline__

#define S_BARRIER() asm volatile("s_barrier" ::: "memory")
#define VMCNT0()    asm volatile("s_waitcnt vmcnt(0)" ::: "memory")
#define VMCNT4()    asm volatile("s_waitcnt vmcnt(4)" ::: "memory")
#define VMCNT16()   asm volatile("s_waitcnt vmcnt(16)" ::: "memory")
#define SCHED0()    __builtin_amdgcn_sched_barrier(0)

#if __has_builtin(__builtin_amdgcn_exp2f)
#define EXP2(x) __builtin_amdgcn_exp2f(x)
#else
#define EXP2(x) exp2f(x)
#endif

DEV uint32_t pk2bf(float lo, float hi) {
  union { __bf16 h[2]; uint32_t u; } x;
  x.h[0] = (__bf16)lo; x.h[1] = (__bf16)hi; return x.u;
}

// ---------------- fused f32 -> bf16 convert (x | wqkv | wout) ----------------
__global__ __launch_bounds__(256) void k_cvt3(const float* __restrict__ s0,
                                              const float* __restrict__ s1,
                                              const float* __restrict__ s2,
                                              bf16_t* __restrict__ dst) {
  long i = (long)(blockIdx.x * 256 + threadIdx.x) * 4;
  const float* src;
  long off;
  if (i < 8388608)        { src = s0; off = i; }
  else if (i < 16777216)  { src = s1; off = i - 8388608; }
  else                    { src = s2; off = i - 16777216; }
  const float4 v = *reinterpret_cast<const float4*>(src + off);
  union { bf16_t h[4]; uint2 u; } o;
  o.h[0] = (bf16_t)v.x; o.h[1] = (bf16_t)v.y;
  o.h[2] = (bf16_t)v.z; o.h[3] = (bf16_t)v.w;
  *reinterpret_cast<uint2*>(dst + i) = o.u;
}

// ============ shared macros for the counted-vmcnt GEMM templates ============
#define RD_A4(dst, base, MF)                                              \
  _Pragma("unroll") for (int j_ = 0; j_ < 4; ++j_)                        \
  _Pragma("unroll") for (int kk_ = 0; kk_ < 2; ++kk_) {                   \
    int p_ = (wm*128 + ((MF)+j_)*16 + c16)*128 + kk_*64 + g*16;           \
    p_ ^= ((p_>>9)&1)<<5;                                                 \
    dst[j_][kk_] = *reinterpret_cast<const bf16x8*>((const char*)(base) + p_); }

#define RD_B_ALL(dst, base)                                               \
  _Pragma("unroll") for (int i_ = 0; i_ < 4; ++i_)                        \
  _Pragma("unroll") for (int kk_ = 0; kk_ < 2; ++kk_) {                   \
    int p_ = (wn*64 + i_*16 + c16)*128 + kk_*64 + g*16;                   \
    p_ ^= ((p_>>9)&1)<<5;                                                 \
    dst[i_][kk_] = *reinterpret_cast<const bf16x8*>((const char*)(base) + p_); }

#define RD_B2(dst, base)                                                  \
  _Pragma("unroll") for (int i_ = 0; i_ < 2; ++i_)                        \
  _Pragma("unroll") for (int kk_ = 0; kk_ < 2; ++kk_) {                   \
    int p_ = (wn*32 + i_*16 + c16)*128 + kk_*64 + g*16;                   \
    p_ ^= ((p_>>9)&1)<<5;                                                 \
    dst[i_][kk_] = *reinterpret_cast<const bf16x8*>((const char*)(base) + p_); }

#define MM_Q(aa, MB, NB)                                                  \
  _Pragma("unroll") for (int j_ = 0; j_ < 4; ++j_)                        \
  _Pragma("unroll") for (int i_ = 0; i_ < 2; ++i_)                        \
  _Pragma("unroll") for (int kk_ = 0; kk_ < 2; ++kk_)                     \
    acc[(MB)+j_][(NB)+i_] = __builtin_amdgcn_mfma_f32_16x16x32_bf16(      \
        aa[j_][kk_], bF[(NB)+i_][kk_], acc[(MB)+j_][(NB)+i_], 0, 0, 0);

#define MM_OG(aa, MB)                                                     \
  _Pragma("unroll") for (int j_ = 0; j_ < 4; ++j_)                        \
  _Pragma("unroll") for (int i_ = 0; i_ < 2; ++i_)                        \
  _Pragma("unroll") for (int kk_ = 0; kk_ < 2; ++kk_)                     \
    acc[(MB)+j_][i_] = __builtin_amdgcn_mfma_f32_16x16x32_bf16(           \
        aa[j_][kk_], bG[i_][kk_], acc[(MB)+j_][i_], 0, 0, 0);

#define STAGE_A(dstbase, half, tt)                                        \
  _Pragma("unroll") for (int j_ = 0; j_ < 2; ++j_)                        \
    __builtin_amdgcn_global_load_lds(                                     \
        (const AS1 void*)(Ag + srcA[half][j_] + (tt)*64),                 \
        (AS3 void*)((char*)(dstbase) + ((half)*1024 + 512*j_ + wuni)*16), \
        16, 0, 0);

#define STAGE_B(dstbase, half, tt)                                        \
  _Pragma("unroll") for (int j_ = 0; j_ < 2; ++j_)                        \
    __builtin_amdgcn_global_load_lds(                                     \
        (const AS1 void*)(Bg + srcB[half][j_] + (tt)*64),                 \
        (AS3 void*)((char*)(dstbase) + ((half)*1024 + 512*j_ + wuni)*16), \
        16, 0, 0);

#define STAGE_B2(dstbase, tt)                                             \
  _Pragma("unroll") for (int j_ = 0; j_ < 2; ++j_)                        \
    __builtin_amdgcn_global_load_lds(                                     \
        (const AS1 void*)(Bg + srcB2[j_] + (tt)*64),                      \
        (AS3 void*)((char*)(dstbase) + (512*j_ + wuni)*16), 16, 0, 0);

// ================= 256x256 counted-vmcnt GEMM (QKV projection) =================
__global__ __launch_bounds__(512, 2) void k_gemm256(
    const bf16_t* __restrict__ Ag, const bf16_t* __restrict__ Bg,
    void* __restrict__ Cv, int M, int N, int K, int out_bf16)
{
  extern __shared__ char smemraw[];
  const int tid = threadIdx.x;
  const int w = tid >> 6, l = tid & 63;
  const int wm = w >> 2, wn = w & 3;
  const int c16 = l & 15, g = l >> 4;
  const int wuni = tid & 0x1C0;          // w*64, wave-uniform

  const int nwg = gridDim.x, cpx = nwg >> 3;
  const int bid = blockIdx.x;
  const int L = (bid & 7) * cpx + (bid >> 3);
  const int nbx = N >> 8;
  const int m0 = (L / nbx) * 256, n0 = (L % nbx) * 256;

  int srcA[2][2], srcB[2][2];
#pragma unroll
  for (int half = 0; half < 2; ++half)
#pragma unroll
    for (int j = 0; j < 2; ++j) {
      int ch = half * 1024 + 512 * j + tid;
      int cc = ch ^ (((ch >> 5) & 1) << 1);
      int row = cc >> 3, c8 = (cc & 7) * 8;
      srcA[half][j] = (m0 + row) * K + c8;
      srcB[half][j] = (n0 + row) * K + c8;
    }

  f32x4 acc[8][4] = {};
  bf16x8 aF[4][2], bF[4][2];

  char* const Ab0 = smemraw;
  char* const Ab1 = smemraw + 32768;
  char* const Bb0 = smemraw + 65536;
  char* const Bb1 = smemraw + 98304;

  const int NT = K >> 6;

  STAGE_B(Bb0, 0, 0); STAGE_B(Bb0, 1, 0);
  STAGE_A(Ab0, 0, 0); STAGE_A(Ab0, 1, 0);
  VMCNT0();
  S_BARRIER();
  RD_B_ALL(bF, Bb0);

#pragma unroll 1
  for (int t = 0; t < NT; ++t) {
    char* const Asp = (t & 1) ? Ab1 : Ab0;
    char* const Asn = (t & 1) ? Ab0 : Ab1;
    char* const Bsn = (t & 1) ? Bb0 : Bb1;
    const bool more = (t + 1 < NT);

    VMCNT0();
    if (more) { STAGE_B(Bsn, 0, t + 1); }
    S_BARRIER();
    RD_A4(aF, Asp, 0);
    __builtin_amdgcn_s_setprio(1);
    MM_Q(aF, 0, 0);
    __builtin_amdgcn_s_setprio(0); SCHED0();
    S_BARRIER();

    if (more) { STAGE_B(Bsn, 1, t + 1); }
    S_BARRIER();
    __builtin_amdgcn_s_setprio(1);
    MM_Q(aF, 0, 2);
    __builtin_amdgcn_s_setprio(0); SCHED0();
    S_BARRIER();

    if (more) { STAGE_A(Asn, 0, t + 1); }
    S_BARRIER();
    RD_A4(aF, Asp, 4);
    __builtin_amdgcn_s_setprio(1);
    MM_Q(aF, 4, 0);
    __builtin_amdgcn_s_setprio(0); SCHED0();
    S_BARRIER();

    if (more) { STAGE_A(Asn, 1, t + 1); VMCNT4(); }
    S_BARRIER();
    __builtin_amdgcn_s_setprio(1);
    MM_Q(aF, 4, 2);
    __builtin_amdgcn_s_setprio(0); SCHED0();
    if (more) { RD_B_ALL(bF, Bsn); }
    S_BARRIER();
  }

#pragma unroll
  for (int mf = 0; mf < 8; ++mf)
#pragma unroll
    for (int nf = 0; nf < 4; ++nf) {
      const int cc = n0 + wn * 64 + nf * 16 + c16;
#pragma unroll
      for (int r = 0; r < 4; ++r) {
        const int rr = m0 + wm * 128 + mf * 16 + g * 4 + r;
        if (out_bf16)
          ((bf16_t*)Cv)[(size_t)rr * N + cc] = (bf16_t)acc[mf][nf][r];
        else
          ((float*)Cv)[(size_t)rr * N + cc] = acc[mf][nf][r];
      }
    }
}

// ================= 256x128 counted-vmcnt GEMM (out projection, f32 out) =================
__global__ __launch_bounds__(512, 2) void k_og(
    const bf16_t* __restrict__ Ag, const bf16_t* __restrict__ Bg,
    float* __restrict__ Cv, int M, int N, int K)
{
  extern __shared__ char smemraw[];
  const int tid = threadIdx.x;
  const int w = tid >> 6, l = tid & 63;
  const int wm = w >> 2, wn = w & 3;
  const int c16 = l & 15, g = l >> 4;
  const int wuni = tid & 0x1C0;

  const int nwg = gridDim.x, cpx = nwg >> 3;
  const int bid = blockIdx.x;
  const int L = (bid & 7) * cpx + (bid >> 3);
  const int nbx = N >> 7;
  const int m0 = (L / nbx) * 256, n0 = (L % nbx) * 128;

  int srcA[2][2], srcB2[2];
#pragma unroll
  for (int half = 0; half < 2; ++half)
#pragma unroll
    for (int j = 0; j < 2; ++j) {
      int ch = half * 1024 + 512 * j + tid;
      int cc = ch ^ (((ch >> 5) & 1) << 1);
      int row = cc >> 3, c8 = (cc & 7) * 8;
      srcA[half][j] = (m0 + row) * K + c8;
    }
#pragma unroll
  for (int j = 0; j < 2; ++j) {
    int ch = 512 * j + tid;
    int cc = ch ^ (((ch >> 5) & 1) << 1);
    int row = cc >> 3, c8 = (cc & 7) * 8;
    srcB2[j] = (n0 + row) * K + c8;
  }

  f32x4 acc[8][2] = {};
  bf16x8 aF[4][2], bG[2][2];

  char* const Ab0 = smemraw;
  char* const Ab1 = smemraw + 32768;
  char* const Bb0 = smemraw + 65536;
  char* const Bb1 = smemraw + 81920;

  const int NT = K >> 6;

  STAGE_B2(Bb0, 0);
  STAGE_A(Ab0, 0, 0); STAGE_A(Ab0, 1, 0);
  VMCNT0();
  S_BARRIER();
  RD_B2(bG, Bb0);

#pragma unroll 1
  for (int t = 0; t < NT; ++t) {
    char* const Asp = (t & 1) ? Ab1 : Ab0;
    char* const Asn = (t & 1) ? Ab0 : Ab1;
    char* const Bsn = (t & 1) ? Bb0 : Bb1;
    const bool more = (t + 1 < NT);

    VMCNT0();
    if (more) { STAGE_B2(Bsn, t + 1); STAGE_A(Asn, 0, t + 1); }
    S_BARRIER();
    RD_A4(aF, Asp, 0);
    __builtin_amdgcn_s_setprio(1);
    MM_OG(aF, 0);
    __builtin_amdgcn_s_setprio(0); SCHED0();
    S_BARRIER();

    if (more) { STAGE_A(Asn, 1, t + 1); VMCNT4(); }
    S_BARRIER();
    RD_A4(aF, Asp, 4);
    __builtin_amdgcn_s_setprio(1);
    MM_OG(aF, 4);
    __builtin_amdgcn_s_setprio(0); SCHED0();
    if (more) { RD_B2(bG, Bsn); }
    S_BARRIER();
  }

#pragma unroll
  for (int mf = 0; mf < 8; ++mf)
#pragma unroll
    for (int nf = 0; nf < 2; ++nf) {
      const int cc = n0 + wn * 32 + nf * 16 + c16;
#pragma unroll
      for (int r = 0; r < 4; ++r) {
        const int rr = m0 + wm * 128 + mf * 16 + g * 4 + r;
        Cv[(size_t)rr * N + cc] = acc[mf][nf][r];
      }
    }
}

// ------- merged prep: RMSNorm+RoPE for Q/K  |  V transpose -------
__global__ __launch_bounds__(256) void k_prep(
    const bf16_t* __restrict__ qkv, const float* __restrict__ freqs,
    const float* __restrict__ qw, const float* __restrict__ kw,
    bf16_t* __restrict__ Qd, bf16_t* __restrict__ Kd,
    bf16_t* __restrict__ Vt)
{
  __shared__ bf16_t vt[64][136];
  const int bid = blockIdx.x;
  if (bid < 24576) {
    const int w = threadIdx.x >> 6, l = threadIdx.x & 63;
    const int R = bid * 4 + w;                 // [0, 98304)
    const int j = R >> 12;                     // 0..23
    const int token = R & 4095;
    const int s = token & 2047, b = token >> 11;
    const bool isq = (j < 16);
    const int col0 = isq ? (j << 7) : (2048 + ((j - 16) << 7));

    union { uint32_t u; __bf16 h[2]; } xin;
    xin.u = *reinterpret_cast<const uint32_t*>(qkv + (size_t)token * 4096 + col0 + 2 * l);
    float x0 = (float)xin.h[0], x1 = (float)xin.h[1];
    float ss = x0 * x0 + x1 * x1;
#pragma unroll
    for (int d = 1; d < 64; d <<= 1) ss += __shfl_xor(ss, d, 64);
    const float rn = rsqrtf(ss * (1.0f / 128.0f) + 1.1920929e-7f);
    const float2 wv = *reinterpret_cast<const float2*>((isq ? qw : kw) + 2 * l);
    const float y0 = x0 * rn * wv.x, y1 = x1 * rn * wv.y;
    const float4 f = *reinterpret_cast<const float4*>(freqs + (size_t)s * 256 + l * 4);
    float o0 = f.x * y0 + f.y * y1;   // cos*y0 - sin*y1
    float o1 = f.z * y0 + f.w * y1;   // sin*y0 + cos*y1
    if (isq) { o0 *= 0.1275187989014331f; o1 *= 0.1275187989014331f; }  // HD^-0.5 * log2(e)
    const uint32_t pk = pk2bf(o0, o1);
    if (isq)
      *reinterpret_cast<uint32_t*>(Qd + ((size_t)(b * 16 + j) * 2048 + s) * 128 + 2 * l) = pk;
    else
      *reinterpret_cast<uint32_t*>(Kd + ((size_t)(b * 8 + (j - 16)) * 2048 + s) * 128 + 2 * l) = pk;
  } else {
    const int vb = bid - 24576;      // 512 = 2*8*32
    const int tid = threadIdx.x;
    const int st = vb & 31, kh = (vb >> 5) & 7, b = vb >> 8;
    const int s0 = st * 64;
#pragma unroll
    for (int i = 0; i < 4; ++i) {
      int ch = tid + 256 * i;
      int srow = ch >> 4, d8 = ch & 15;
      bf16x8 v = *reinterpret_cast<const bf16x8*>(
          qkv + (size_t)(b * 2048 + s0 + srow) * 4096 + 3072 + kh * 128 + d8 * 8);
      *reinterpret_cast<bf16x8*>(&vt[srow][d8 * 8]) = v;
    }
    __syncthreads();
    const int d = tid >> 1, sc = tid & 1;
    bf16_t* dst = Vt + ((size_t)(b * 8 + kh) * 128 + d) * 2048 + s0 + 32 * sc;
#pragma unroll
    for (int grp = 0; grp < 4; ++grp) {
      uint32_t pk[4];
#pragma unroll
      for (int q = 0; q < 4; ++q) {
        int jj = 32 * sc + grp * 8 + q * 2;
        union { __bf16 h[2]; uint32_t u; } e;
        e.h[0] = vt[jj][d]; e.h[1] = vt[jj + 1][d];
        pk[q] = e.u;
      }
      uint4 o; o.x = pk[0]; o.y = pk[1]; o.z = pk[2]; o.w = pk[3];
      *reinterpret_cast<uint4*>(dst + grp * 8) = o;
    }
  }
}

// ---------------- Flash attention: q=64/wave (LDS-read amortization) ----------------
// LDS-BW analysis: each wave reads the full 32KB K+V tile per step; at q=32/wave
// (2048 waves) that is 8MB/CU = 39us floor. Each wave now owns TWO 32-q blocks:
// every kf/vf LDS read feeds 2 MFMAs -> half the waves, same reads/wave, floor ~20us.
// 2 waves/block, VGPR ~280 (launch_bounds(128,1) -> cap 512, NO spill), LDS 64KB dbuf.
__global__ __launch_bounds__(128, 1) void k_attn(
    const bf16_t* __restrict__ Qd, const bf16_t* __restrict__ Kd,
    const bf16_t* __restrict__ Vt, bf16_t* __restrict__ O)
{
  __shared__ bf16_t kbuf[2][64 * 128];   // [key][d], XOR-swizzled
  __shared__ bf16_t vbuf[2][128 * 64];   // [d][key], XOR-swizzled
  const int tid = threadIdx.x;
  const int w = tid >> 6, l = tid & 63;
  const int c = l & 31, h2 = l >> 5;
  const int bid = blockIdx.x;            // 512 = 2*16*16
  const int qt = bid & 15, h = (bid >> 4) & 15, b = bid >> 8;
  const int kvh = h >> 1;                // NREP=2
  const bf16_t* Qg = Qd + ((size_t)(b * 16 + h) * 2048 + qt * 128 + w * 64) * 128;
  const bf16_t* Kg = Kd + ((size_t)(b * 8 + kvh) * 2048) * 128;
  const bf16_t* Vg = Vt + ((size_t)(b * 8 + kvh) * 128) * 2048;

  bf16x8 qf0[8], qf1[8];
#pragma unroll
  for (int s = 0; s < 8; ++s) {
    qf0[s] = *reinterpret_cast<const bf16x8*>(Qg + (size_t)c * 128 + s * 16 + h2 * 8);
    qf1[s] = *reinterpret_cast<const bf16x8*>(Qg + (size_t)(32 + c) * 128 + s * 16 + h2 * 8);
  }

  f32x16 oacc0[4] = {}, oacc1[4] = {};
  float la0 = 0.f, la1 = 0.f, la2 = 0.f, la3 = 0.f;
  float lb0 = 0.f, lb1 = 0.f, lb2 = 0.f, lb3 = 0.f;

  auto stage = [&](int buf, int kt) {
#pragma unroll
    for (int i = 0; i < 8; ++i) {
      int ch = tid + 128 * i;
      { // K tile: LDS linear, source pre-swizzled (byte ^= (key&7)<<4)
        int key = ch >> 4, d16 = ch & 15;
        int soff = key * 256 + ((d16 * 16) ^ ((key & 7) << 4));
        __builtin_amdgcn_global_load_lds(
            (const AS1 void*)((const char*)Kg + (size_t)kt * 64 * 256 + soff),
            (AS3 void*)((char*)&kbuf[buf][0] + ch * 16), 16, 0, 0);
      }
      { // Vt tile: source pre-swizzled (k-chunk ^= d&7)
        int d = ch >> 3, k8 = (ch & 7) ^ (d & 7);
        __builtin_amdgcn_global_load_lds(
            (const AS1 void*)(Vg + (size_t)d * 2048 + kt * 64 + k8 * 8),
            (AS3 void*)((char*)&vbuf[buf][0] + ch * 16), 16, 0, 0);
      }
    }
  };

  auto compute = [&](int buf) {
    f32x16 s0[2] = {}, s1[2] = {};
    const char* kb = (const char*)&kbuf[buf][0];
    __builtin_amdgcn_s_setprio(1);
#pragma unroll
    for (int m = 0; m < 2; ++m)
#pragma unroll
      for (int s = 0; s < 8; ++s) {
        int byte = (m * 32 + c) * 256 + ((s * 32 + h2 * 16) ^ ((c & 7) << 4));
        bf16x8 kf = *reinterpret_cast<const bf16x8*>(kb + byte);
        s0[m] = __builtin_amdgcn_mfma_f32_32x32x16_bf16(kf, qf0[s], s0[m], 0, 0, 0);
        s1[m] = __builtin_amdgcn_mfma_f32_32x32x16_bf16(kf, qf1[s], s1[m], 0, 0, 0);
      }
    __builtin_amdgcn_s_setprio(0);

#pragma unroll
    for (int m = 0; m < 2; ++m)
#pragma unroll
      for (int r = 0; r < 16; r += 4) {
        float a0 = EXP2(s0[m][r + 0]);
        float a1 = EXP2(s0[m][r + 1]);
        float a2 = EXP2(s0[m][r + 2]);
        float a3 = EXP2(s0[m][r + 3]);
        s0[m][r + 0] = a0; s0[m][r + 1] = a1; s0[m][r + 2] = a2; s0[m][r + 3] = a3;
        la0 += a0; la1 += a1; la2 += a2; la3 += a3;
        float b0 = EXP2(s1[m][r + 0]);
        float b1 = EXP2(s1[m][r + 1]);
        float b2 = EXP2(s1[m][r + 2]);
        float b3 = EXP2(s1[m][r + 3]);
        s1[m][r + 0] = b0; s1[m][r + 1] = b1; s1[m][r + 2] = b2; s1[m][r + 3] = b3;
        lb0 += b0; lb1 += b1; lb2 += b2; lb3 += b3;
      }

    const char* vb = (const char*)&vbuf[buf][0];
#pragma unroll
    for (int t = 0; t < 4; ++t) {
      const int m = t >> 1, q2i = t & 1;
      uint32_t u0 = pk2bf(s0[m][8 * q2i + 0], s0[m][8 * q2i + 1]);
      uint32_t u1 = pk2bf(s0[m][8 * q2i + 2], s0[m][8 * q2i + 3]);
      uint32_t u2 = pk2bf(s0[m][8 * q2i + 4], s0[m][8 * q2i + 5]);
      uint32_t u3 = pk2bf(s0[m][8 * q2i + 6], s0[m][8 * q2i + 7]);
      auto r02 = __builtin_amdgcn_permlane32_swap((int)u0, (int)u2, false, false);
      auto r13 = __builtin_amdgcn_permlane32_swap((int)u1, (int)u3, false, false);
      union { uint32_t u[4]; bf16x8 v; } pb0;
      pb0.u[0] = (uint32_t)r02[0]; pb0.u[1] = (uint32_t)r13[0];
      pb0.u[2] = (uint32_t)r02[1]; pb0.u[3] = (uint32_t)r13[1];
      uint32_t w0 = pk2bf(s1[m][8 * q2i + 0], s1[m][8 * q2i + 1]);
      uint32_t w1 = pk2bf(s1[m][8 * q2i + 2], s1[m][8 * q2i + 3]);
      uint32_t w2 = pk2bf(s1[m][8 * q2i + 4], s1[m][8 * q2i + 5]);
      uint32_t w3 = pk2bf(s1[m][8 * q2i + 6], s1[m][8 * q2i + 7]);
      auto t02 = __builtin_amdgcn_permlane32_swap((int)w0, (int)w2, false, false);
      auto t13 = __builtin_amdgcn_permlane32_swap((int)w1, (int)w3, false, false);
      union { uint32_t u[4]; bf16x8 v; } pb1;
      pb1.u[0] = (uint32_t)t02[0]; pb1.u[1] = (uint32_t)t13[0];
      pb1.u[2] = (uint32_t)t02[1]; pb1.u[3] = (uint32_t)t13[1];
      __builtin_amdgcn_s_setprio(1);
#pragma unroll
      for (int df = 0; df < 4; ++df) {
        int byte = (df * 32 + c) * 128 + ((t * 32 + h2 * 16) ^ ((c & 7) << 4));
        bf16x8 vf = *reinterpret_cast<const bf16x8*>(vb + byte);
        oacc0[df] = __builtin_amdgcn_mfma_f32_32x32x16_bf16(vf, pb0.v, oacc0[df], 0, 0, 0);
        oacc1[df] = __builtin_amdgcn_mfma_f32_32x32x16_bf16(vf, pb1.v, oacc1[df], 0, 0, 0);
      }
      __builtin_amdgcn_s_setprio(0);
    }
  };

  stage(0, 0);
#pragma unroll 1
  for (int kt = 0; kt < 31; ++kt) {
    stage((kt + 1) & 1, kt + 1);   // 16 loads/thread in flight
    VMCNT16();                     // drain tile kt's loads only
    S_BARRIER();
    compute(kt & 1);
    S_BARRIER();
  }
  VMCNT0();
  S_BARRIER();
  compute(1);

  float lrun0 = (la0 + la1) + (la2 + la3);
  lrun0 += __shfl_xor(lrun0, 32, 64);
  float lrun1 = (lb0 + lb1) + (lb2 + lb3);
  lrun1 += __shfl_xor(lrun1, 32, 64);
  const float inv0 = 1.0f / lrun0;
  const float inv1 = 1.0f / lrun1;
  bf16_t* Og0 = O + ((size_t)(b * 2048 + qt * 128 + w * 64 + c) * 2048) + h * 128;
  bf16_t* Og1 = Og0 + (size_t)32 * 2048;
#pragma unroll
  for (int df = 0; df < 4; ++df)
#pragma unroll
    for (int rg = 0; rg < 4; ++rg) {
      uint32_t a0 = pk2bf(oacc0[df][rg * 4 + 0] * inv0, oacc0[df][rg * 4 + 1] * inv0);
      uint32_t a1 = pk2bf(oacc0[df][rg * 4 + 2] * inv0, oacc0[df][rg * 4 + 3] * inv0);
      uint2 wa; wa.x = a0; wa.y = a1;
      *reinterpret_cast<uint2*>(Og0 + df * 32 + 8 * rg + 4 * h2) = wa;
      uint32_t b0w = pk2bf(oacc1[df][rg * 4 + 0] * inv1, oacc1[df][rg * 4 + 1] * inv1);
      uint32_t b1w = pk2bf(oacc1[df][rg * 4 + 2] * inv1, oacc1[df][rg * 4 + 3] * inv1);
      uint2 wb; wb.x = b0w; wb.y = b1w;
      *reinterpret_cast<uint2*>(Og1 + df * 32 + 8 * rg + 4 * h2) = wb;
    }
}

// ---------------- host launcher ----------------
extern "C" void kernel_launch(void* const* d_in, const int* in_sizes, int n_in,
                              void* d_out, int out_size, void* d_ws, size_t ws_size,
                              hipStream_t stream)
{
  const float* x     = (const float*)d_in[0];
  const float* freqs = (const float*)d_in[2];
  const float* wqkv  = (const float*)d_in[3];
  const float* wout  = (const float*)d_in[4];
  const float* qw    = (const float*)d_in[5];
  const float* kw    = (const float*)d_in[6];
  float* out = (float*)d_out;

  bf16_t* Xb   = (bf16_t*)d_ws;           // 4096x2048
  bf16_t* Wqb  = Xb  + 8388608;           // 4096x2048
  bf16_t* Wob  = Wqb + 8388608;           // 2048x2048
  bf16_t* qkvb = Wob + 4194304;           // 4096x4096 (later aliased as O)
  bf16_t* Qdp  = qkvb + 16777216;         // [2][16][2048][128]
  bf16_t* Kdp  = Qdp + 8388608;           // [2][8][2048][128]
  bf16_t* Vtp  = Kdp + 4194304;           // [2][8][128][2048]
  bf16_t* Ob   = qkvb;                    // alias: qkv dead after preps

  (void)hipFuncSetAttribute((const void*)k_gemm256,
                            hipFuncAttributeMaxDynamicSharedMemorySize, 131072);
  (void)hipFuncSetAttribute((const void*)k_og,
                            hipFuncAttributeMaxDynamicSharedMemorySize, 98304);

  k_cvt3<<<20480, 256, 0, stream>>>(x, wqkv, wout, Xb);
  k_gemm256<<<256, 512, 131072, stream>>>(Xb, Wqb, qkvb, 4096, 4096, 2048, 1);
  k_prep<<<25088, 256, 0, stream>>>(qkvb, freqs, qw, kw, Qdp, Kdp, Vtp);
  k_attn<<<512, 128, 0, stream>>>(Qdp, Kdp, Vtp, Ob);
  k_og<<<256, 512, 98304, stream>>>(Ob, Wob, out, 4096, 2048, 2048);
}

// Round 12
// 234.107 us; speedup vs baseline: 1.0670x; 1.0670x over previous
//
#include <hip/hip_runtime.h>
#include <hip/hip_bf16.h>
#include <cstdint>

typedef __bf16 bf16_t;
typedef __attribute__((ext_vector_type(8)))  __bf16 bf16x8;
typedef __attribute__((ext_vector_type(4)))  float  f32x4;
typedef __attribute__((ext_vector_type(16))) float  f32x16;

#define AS1 __attribute__((address_space(1)))
#define AS3 __attribute__((address_space(3)))
#define DEV __device__ __forceinline__

#define S_BARRIER() asm volatile("s_barrier" ::: "memory")
#define VMCNT0()    asm volatile("s_waitcnt vmcnt(0)" ::: "memory")
#define VMCNT4()    asm volatile("s_waitcnt vmcnt(4)" ::: "memory")
#define VMCNT8()    asm volatile("s_waitcnt vmcnt(8)" ::: "memory")
#define SCHED0()    __builtin_amdgcn_sched_barrier(0)

#if __has_builtin(__builtin_amdgcn_exp2f)
#define EXP2(x) __builtin_amdgcn_exp2f(x)
#else
#define EXP2(x) exp2f(x)
#endif

DEV uint32_t pk2bf(float lo, float hi) {
  union { __bf16 h[2]; uint32_t u; } x;
  x.h[0] = (__bf16)lo; x.h[1] = (__bf16)hi; return x.u;
}

// ---------------- fused f32 -> bf16 convert (x | wqkv | wout) ----------------
__global__ __launch_bounds__(256) void k_cvt3(const float* __restrict__ s0,
                                              const float* __restrict__ s1,
                                              const float* __restrict__ s2,
                                              bf16_t* __restrict__ dst) {
  long i = (long)(blockIdx.x * 256 + threadIdx.x) * 4;
  const float* src;
  long off;
  if (i < 8388608)        { src = s0; off = i; }
  else if (i < 16777216)  { src = s1; off = i - 8388608; }
  else                    { src = s2; off = i - 16777216; }
  const float4 v = *reinterpret_cast<const float4*>(src + off);
  union { bf16_t h[4]; uint2 u; } o;
  o.h[0] = (bf16_t)v.x; o.h[1] = (bf16_t)v.y;
  o.h[2] = (bf16_t)v.z; o.h[3] = (bf16_t)v.w;
  *reinterpret_cast<uint2*>(dst + i) = o.u;
}

// ============ shared macros for the counted-vmcnt GEMM templates ============
#define RD_A4(dst, base, MF)                                              \
  _Pragma("unroll") for (int j_ = 0; j_ < 4; ++j_)                        \
  _Pragma("unroll") for (int kk_ = 0; kk_ < 2; ++kk_) {                   \
    int p_ = (wm*128 + ((MF)+j_)*16 + c16)*128 + kk_*64 + g*16;           \
    p_ ^= ((p_>>9)&1)<<5;                                                 \
    dst[j_][kk_] = *reinterpret_cast<const bf16x8*>((const char*)(base) + p_); }

#define RD_B_ALL(dst, base)                                               \
  _Pragma("unroll") for (int i_ = 0; i_ < 4; ++i_)                        \
  _Pragma("unroll") for (int kk_ = 0; kk_ < 2; ++kk_) {                   \
    int p_ = (wn*64 + i_*16 + c16)*128 + kk_*64 + g*16;                   \
    p_ ^= ((p_>>9)&1)<<5;                                                 \
    dst[i_][kk_] = *reinterpret_cast<const bf16x8*>((const char*)(base) + p_); }

#define RD_B2(dst, base)                                                  \
  _Pragma("unroll") for (int i_ = 0; i_ < 2; ++i_)                        \
  _Pragma("unroll") for (int kk_ = 0; kk_ < 2; ++kk_) {                   \
    int p_ = (wn*32 + i_*16 + c16)*128 + kk_*64 + g*16;                   \
    p_ ^= ((p_>>9)&1)<<5;                                                 \
    dst[i_][kk_] = *reinterpret_cast<const bf16x8*>((const char*)(base) + p_); }

#define MM_Q(aa, MB, NB)                                                  \
  _Pragma("unroll") for (int j_ = 0; j_ < 4; ++j_)                        \
  _Pragma("unroll") for (int i_ = 0; i_ < 2; ++i_)                        \
  _Pragma("unroll") for (int kk_ = 0; kk_ < 2; ++kk_)                     \
    acc[(MB)+j_][(NB)+i_] = __builtin_amdgcn_mfma_f32_16x16x32_bf16(      \
        aa[j_][kk_], bF[(NB)+i_][kk_], acc[(MB)+j_][(NB)+i_], 0, 0, 0);

#define MM_OG(aa, MB)                                                     \
  _Pragma("unroll") for (int j_ = 0; j_ < 4; ++j_)                        \
  _Pragma("unroll") for (int i_ = 0; i_ < 2; ++i_)                        \
  _Pragma("unroll") for (int kk_ = 0; kk_ < 2; ++kk_)                     \
    acc[(MB)+j_][i_] = __builtin_amdgcn_mfma_f32_16x16x32_bf16(           \
        aa[j_][kk_], bG[i_][kk_], acc[(MB)+j_][i_], 0, 0, 0);

#define STAGE_A(dstbase, half, tt)                                        \
  _Pragma("unroll") for (int j_ = 0; j_ < 2; ++j_)                        \
    __builtin_amdgcn_global_load_lds(                                     \
        (const AS1 void*)(Ag + srcA[half][j_] + (tt)*64),                 \
        (AS3 void*)((char*)(dstbase) + ((half)*1024 + 512*j_ + wuni)*16), \
        16, 0, 0);

#define STAGE_B(dstbase, half, tt)                                        \
  _Pragma("unroll") for (int j_ = 0; j_ < 2; ++j_)                        \
    __builtin_amdgcn_global_load_lds(                                     \
        (const AS1 void*)(Bg + srcB[half][j_] + (tt)*64),                 \
        (AS3 void*)((char*)(dstbase) + ((half)*1024 + 512*j_ + wuni)*16), \
        16, 0, 0);

#define STAGE_B2(dstbase, tt)                                             \
  _Pragma("unroll") for (int j_ = 0; j_ < 2; ++j_)                        \
    __builtin_amdgcn_global_load_lds(                                     \
        (const AS1 void*)(Bg + srcB2[j_] + (tt)*64),                      \
        (AS3 void*)((char*)(dstbase) + (512*j_ + wuni)*16), 16, 0, 0);

// ================= 256x256 GEMM, A tri-buffered (no A-drain stall) =================
// LDS 160KB: A x3 (32KB each) + B x2 (32KB each).
// Issue per tile t: B0(t+1)@P0, B1(t+1)@P1, A0(t+2)@P2, A1(t+2)@P3.
// Single vmcnt(4)@P3 drains B(t+1) (and all older, incl. A(t+1)); A(t+2) flies.
// => A(t) is 5-6 phases old when read at P0(t): zero exposed HBM latency.
__global__ __launch_bounds__(512, 2) void k_gemm256(
    const bf16_t* __restrict__ Ag, const bf16_t* __restrict__ Bg,
    void* __restrict__ Cv, int M, int N, int K, int out_bf16)
{
  extern __shared__ char smemraw[];
  const int tid = threadIdx.x;
  const int w = tid >> 6, l = tid & 63;
  const int wm = w >> 2, wn = w & 3;
  const int c16 = l & 15, g = l >> 4;
  const int wuni = tid & 0x1C0;          // w*64, wave-uniform

  const int nwg = gridDim.x, cpx = nwg >> 3;
  const int bid = blockIdx.x;
  const int L = (bid & 7) * cpx + (bid >> 3);
  const int nbx = N >> 8;
  const int m0 = (L / nbx) * 256, n0 = (L % nbx) * 256;

  int srcA[2][2], srcB[2][2];
#pragma unroll
  for (int half = 0; half < 2; ++half)
#pragma unroll
    for (int j = 0; j < 2; ++j) {
      int ch = half * 1024 + 512 * j + tid;
      int cc = ch ^ (((ch >> 5) & 1) << 1);
      int row = cc >> 3, c8 = (cc & 7) * 8;
      srcA[half][j] = (m0 + row) * K + c8;
      srcB[half][j] = (n0 + row) * K + c8;
    }

  f32x4 acc[8][4] = {};
  bf16x8 aF[4][2], bF[4][2];

  char* const Ab = smemraw;              // 3 x 32KB
  char* const Bb = smemraw + 98304;      // 2 x 32KB

  const int NT = K >> 6;

  // prologue: B(0)->Bbuf0, A(0)->Abuf0, A(1)->Abuf1; drain B(0)+A(0); read bF(0)
  STAGE_B(Bb, 0, 0); STAGE_B(Bb, 1, 0);
  STAGE_A(Ab, 0, 0); STAGE_A(Ab, 1, 0);
  STAGE_A(Ab + 32768, 0, 1); STAGE_A(Ab + 32768, 1, 1);
  VMCNT4();
  S_BARRIER();
  RD_B_ALL(bF, Bb);

  int aCur = 0;
#pragma unroll 1
  for (int t = 0; t < NT; ++t) {
    char* const Asp  = Ab + aCur * 32768;
    const int aN2    = (aCur >= 1) ? (aCur - 1) : 2;   // (aCur+2)%3
    char* const Asn2 = Ab + aN2 * 32768;
    char* const Bsp  = Bb + (((t + 1) & 1) * 32768);   // buffer of B(t+1)
    const bool m1 = (t + 1 < NT);
    const bool m2 = (t + 2 < NT);

    // -- P0 --
    if (m1) { STAGE_B(Bsp, 0, t + 1); }
    S_BARRIER();
    RD_A4(aF, Asp, 0);
    __builtin_amdgcn_s_setprio(1);
    MM_Q(aF, 0, 0);
    __builtin_amdgcn_s_setprio(0); SCHED0();
    S_BARRIER();

    // -- P1 --
    if (m1) { STAGE_B(Bsp, 1, t + 1); }
    S_BARRIER();
    __builtin_amdgcn_s_setprio(1);
    MM_Q(aF, 0, 2);
    __builtin_amdgcn_s_setprio(0); SCHED0();
    S_BARRIER();

    // -- P2 --
    if (m2) { STAGE_A(Asn2, 0, t + 2); }
    S_BARRIER();
    RD_A4(aF, Asp, 4);
    __builtin_amdgcn_s_setprio(1);
    MM_Q(aF, 4, 0);
    __builtin_amdgcn_s_setprio(0); SCHED0();
    S_BARRIER();

    // -- P3 --
    if (m2)      { STAGE_A(Asn2, 1, t + 2); VMCNT4(); }
    else if (m1) { VMCNT0(); }
    S_BARRIER();
    __builtin_amdgcn_s_setprio(1);
    MM_Q(aF, 4, 2);
    __builtin_amdgcn_s_setprio(0); SCHED0();
    if (m1) { RD_B_ALL(bF, Bsp); }
    S_BARRIER();

    aCur = (aCur < 2) ? (aCur + 1) : 0;
  }

#pragma unroll
  for (int mf = 0; mf < 8; ++mf)
#pragma unroll
    for (int nf = 0; nf < 4; ++nf) {
      const int cc = n0 + wn * 64 + nf * 16 + c16;
#pragma unroll
      for (int r = 0; r < 4; ++r) {
        const int rr = m0 + wm * 128 + mf * 16 + g * 4 + r;
        if (out_bf16)
          ((bf16_t*)Cv)[(size_t)rr * N + cc] = (bf16_t)acc[mf][nf][r];
        else
          ((float*)Cv)[(size_t)rr * N + cc] = acc[mf][nf][r];
      }
    }
}

// ================= 256x128 counted-vmcnt GEMM (out projection, f32 out) =================
__global__ __launch_bounds__(512, 2) void k_og(
    const bf16_t* __restrict__ Ag, const bf16_t* __restrict__ Bg,
    float* __restrict__ Cv, int M, int N, int K)
{
  extern __shared__ char smemraw[];
  const int tid = threadIdx.x;
  const int w = tid >> 6, l = tid & 63;
  const int wm = w >> 2, wn = w & 3;
  const int c16 = l & 15, g = l >> 4;
  const int wuni = tid & 0x1C0;

  const int nwg = gridDim.x, cpx = nwg >> 3;
  const int bid = blockIdx.x;
  const int L = (bid & 7) * cpx + (bid >> 3);
  const int nbx = N >> 7;
  const int m0 = (L / nbx) * 256, n0 = (L % nbx) * 128;

  int srcA[2][2], srcB2[2];
#pragma unroll
  for (int half = 0; half < 2; ++half)
#pragma unroll
    for (int j = 0; j < 2; ++j) {
      int ch = half * 1024 + 512 * j + tid;
      int cc = ch ^ (((ch >> 5) & 1) << 1);
      int row = cc >> 3, c8 = (cc & 7) * 8;
      srcA[half][j] = (m0 + row) * K + c8;
    }
#pragma unroll
  for (int j = 0; j < 2; ++j) {
    int ch = 512 * j + tid;
    int cc = ch ^ (((ch >> 5) & 1) << 1);
    int row = cc >> 3, c8 = (cc & 7) * 8;
    srcB2[j] = (n0 + row) * K + c8;
  }

  f32x4 acc[8][2] = {};
  bf16x8 aF[4][2], bG[2][2];

  char* const Ab0 = smemraw;
  char* const Ab1 = smemraw + 32768;
  char* const Bb0 = smemraw + 65536;
  char* const Bb1 = smemraw + 81920;

  const int NT = K >> 6;

  STAGE_B2(Bb0, 0);
  STAGE_A(Ab0, 0, 0); STAGE_A(Ab0, 1, 0);
  VMCNT0();
  S_BARRIER();
  RD_B2(bG, Bb0);

#pragma unroll 1
  for (int t = 0; t < NT; ++t) {
    char* const Asp = (t & 1) ? Ab1 : Ab0;
    char* const Asn = (t & 1) ? Ab0 : Ab1;
    char* const Bsn = (t & 1) ? Bb0 : Bb1;
    const bool more = (t + 1 < NT);

    VMCNT0();
    if (more) { STAGE_B2(Bsn, t + 1); STAGE_A(Asn, 0, t + 1); }
    S_BARRIER();
    RD_A4(aF, Asp, 0);
    __builtin_amdgcn_s_setprio(1);
    MM_OG(aF, 0);
    __builtin_amdgcn_s_setprio(0); SCHED0();
    S_BARRIER();

    if (more) { STAGE_A(Asn, 1, t + 1); VMCNT4(); }
    S_BARRIER();
    RD_A4(aF, Asp, 4);
    __builtin_amdgcn_s_setprio(1);
    MM_OG(aF, 4);
    __builtin_amdgcn_s_setprio(0); SCHED0();
    if (more) { RD_B2(bG, Bsn); }
    S_BARRIER();
  }

#pragma unroll
  for (int mf = 0; mf < 8; ++mf)
#pragma unroll
    for (int nf = 0; nf < 2; ++nf) {
      const int cc = n0 + wn * 32 + nf * 16 + c16;
#pragma unroll
      for (int r = 0; r < 4; ++r) {
        const int rr = m0 + wm * 128 + mf * 16 + g * 4 + r;
        Cv[(size_t)rr * N + cc] = acc[mf][nf][r];
      }
    }
}

// ------- merged prep: RMSNorm+RoPE for Q/K  |  V transpose -------
__global__ __launch_bounds__(256) void k_prep(
    const bf16_t* __restrict__ qkv, const float* __restrict__ freqs,
    const float* __restrict__ qw, const float* __restrict__ kw,
    bf16_t* __restrict__ Qd, bf16_t* __restrict__ Kd,
    bf16_t* __restrict__ Vt)
{
  __shared__ bf16_t vt[64][136];
  const int bid = blockIdx.x;
  if (bid < 24576) {
    const int w = threadIdx.x >> 6, l = threadIdx.x & 63;
    const int R = bid * 4 + w;                 // [0, 98304)
    const int j = R >> 12;                     // 0..23
    const int token = R & 4095;
    const int s = token & 2047, b = token >> 11;
    const bool isq = (j < 16);
    const int col0 = isq ? (j << 7) : (2048 + ((j - 16) << 7));

    union { uint32_t u; __bf16 h[2]; } xin;
    xin.u = *reinterpret_cast<const uint32_t*>(qkv + (size_t)token * 4096 + col0 + 2 * l);
    float x0 = (float)xin.h[0], x1 = (float)xin.h[1];
    float ss = x0 * x0 + x1 * x1;
#pragma unroll
    for (int d = 1; d < 64; d <<= 1) ss += __shfl_xor(ss, d, 64);
    const float rn = rsqrtf(ss * (1.0f / 128.0f) + 1.1920929e-7f);
    const float2 wv = *reinterpret_cast<const float2*>((isq ? qw : kw) + 2 * l);
    const float y0 = x0 * rn * wv.x, y1 = x1 * rn * wv.y;
    const float4 f = *reinterpret_cast<const float4*>(freqs + (size_t)s * 256 + l * 4);
    float o0 = f.x * y0 + f.y * y1;   // cos*y0 - sin*y1
    float o1 = f.z * y0 + f.w * y1;   // sin*y0 + cos*y1
    if (isq) { o0 *= 0.1275187989014331f; o1 *= 0.1275187989014331f; }  // HD^-0.5 * log2(e)
    const uint32_t pk = pk2bf(o0, o1);
    if (isq)
      *reinterpret_cast<uint32_t*>(Qd + ((size_t)(b * 16 + j) * 2048 + s) * 128 + 2 * l) = pk;
    else
      *reinterpret_cast<uint32_t*>(Kd + ((size_t)(b * 8 + (j - 16)) * 2048 + s) * 128 + 2 * l) = pk;
  } else {
    const int vb = bid - 24576;      // 512 = 2*8*32
    const int tid = threadIdx.x;
    const int st = vb & 31, kh = (vb >> 5) & 7, b = vb >> 8;
    const int s0 = st * 64;
#pragma unroll
    for (int i = 0; i < 4; ++i) {
      int ch = tid + 256 * i;
      int srow = ch >> 4, d8 = ch & 15;
      bf16x8 v = *reinterpret_cast<const bf16x8*>(
          qkv + (size_t)(b * 2048 + s0 + srow) * 4096 + 3072 + kh * 128 + d8 * 8);
      *reinterpret_cast<bf16x8*>(&vt[srow][d8 * 8]) = v;
    }
    __syncthreads();
    const int d = tid >> 1, sc = tid & 1;
    bf16_t* dst = Vt + ((size_t)(b * 8 + kh) * 128 + d) * 2048 + s0 + 32 * sc;
#pragma unroll
    for (int grp = 0; grp < 4; ++grp) {
      uint32_t pk[4];
#pragma unroll
      for (int q = 0; q < 4; ++q) {
        int jj = 32 * sc + grp * 8 + q * 2;
        union { __bf16 h[2]; uint32_t u; } e;
        e.h[0] = vt[jj][d]; e.h[1] = vt[jj + 1][d];
        pk[q] = e.u;
      }
      uint4 o; o.x = pk[0]; o.y = pk[1]; o.z = pk[2]; o.w = pk[3];
      *reinterpret_cast<uint4*>(dst + grp * 8) = o;
    }
  }
}

// ---------------- Flash attention (R7-proven: staged LDS, counted vmcnt) ----------------
__global__ __launch_bounds__(256, 2) void k_attn(
    const bf16_t* __restrict__ Qd, const bf16_t* __restrict__ Kd,
    const bf16_t* __restrict__ Vt, bf16_t* __restrict__ O)
{
  __shared__ bf16_t kbuf[2][64 * 128];   // [key][d], XOR-swizzled
  __shared__ bf16_t vbuf[2][128 * 64];   // [d][key], XOR-swizzled
  const int tid = threadIdx.x;
  const int w = tid >> 6, l = tid & 63;
  const int c = l & 31, h2 = l >> 5;
  const int bid = blockIdx.x;            // 512 = 2*16*16
  const int qt = bid & 15, h = (bid >> 4) & 15, b = bid >> 8;
  const int kvh = h >> 1;                // NREP=2
  const bf16_t* Qg = Qd + ((size_t)(b * 16 + h) * 2048 + qt * 128 + w * 32) * 128;
  const bf16_t* Kg = Kd + ((size_t)(b * 8 + kvh) * 2048) * 128;
  const bf16_t* Vg = Vt + ((size_t)(b * 8 + kvh) * 128) * 2048;

  bf16x8 qf[8];
#pragma unroll
  for (int s = 0; s < 8; ++s)
    qf[s] = *reinterpret_cast<const bf16x8*>(Qg + (size_t)c * 128 + s * 16 + h2 * 8);

  f32x16 oacc[4] = {};
  float l0 = 0.f, l1 = 0.f, l2 = 0.f, l3 = 0.f;

  auto stage = [&](int buf, int kt) {
#pragma unroll
    for (int i = 0; i < 4; ++i) {
      int ch = tid + 256 * i;
      { // K tile: LDS linear, source pre-swizzled (byte ^= (key&7)<<4)
        int key = ch >> 4, d16 = ch & 15;
        int soff = key * 256 + ((d16 * 16) ^ ((key & 7) << 4));
        __builtin_amdgcn_global_load_lds(
            (const AS1 void*)((const char*)Kg + (size_t)kt * 64 * 256 + soff),
            (AS3 void*)((char*)&kbuf[buf][0] + (w * 64 + 256 * i) * 16), 16, 0, 0);
      }
      { // Vt tile: source pre-swizzled (k-chunk ^= d&7)
        int d = ch >> 3, k8 = (ch & 7) ^ (d & 7);
        __builtin_amdgcn_global_load_lds(
            (const AS1 void*)(Vg + (size_t)d * 2048 + kt * 64 + k8 * 8),
            (AS3 void*)((char*)&vbuf[buf][0] + (w * 64 + 256 * i) * 16), 16, 0, 0);
      }
    }
  };

  auto compute = [&](int buf) {
    f32x16 sacc[2] = {};
    const char* kb = (const char*)&kbuf[buf][0];
    __builtin_amdgcn_s_setprio(1);
#pragma unroll
    for (int m = 0; m < 2; ++m)
#pragma unroll
      for (int s = 0; s < 8; ++s) {
        int byte = (m * 32 + c) * 256 + ((s * 32 + h2 * 16) ^ ((c & 7) << 4));
        bf16x8 kf = *reinterpret_cast<const bf16x8*>(kb + byte);
        sacc[m] = __builtin_amdgcn_mfma_f32_32x32x16_bf16(kf, qf[s], sacc[m], 0, 0, 0);
      }
    __builtin_amdgcn_s_setprio(0);

#pragma unroll
    for (int m = 0; m < 2; ++m)
#pragma unroll
      for (int r = 0; r < 16; r += 4) {
        float p0 = EXP2(sacc[m][r + 0]);
        float p1 = EXP2(sacc[m][r + 1]);
        float p2 = EXP2(sacc[m][r + 2]);
        float p3 = EXP2(sacc[m][r + 3]);
        sacc[m][r + 0] = p0; sacc[m][r + 1] = p1;
        sacc[m][r + 2] = p2; sacc[m][r + 3] = p3;
        l0 += p0; l1 += p1; l2 += p2; l3 += p3;
      }

    const char* vb = (const char*)&vbuf[buf][0];
#pragma unroll
    for (int t = 0; t < 4; ++t) {
      const int m = t >> 1, q2i = t & 1;
      uint32_t u0 = pk2bf(sacc[m][8 * q2i + 0], sacc[m][8 * q2i + 1]);
      uint32_t u1 = pk2bf(sacc[m][8 * q2i + 2], sacc[m][8 * q2i + 3]);
      uint32_t u2 = pk2bf(sacc[m][8 * q2i + 4], sacc[m][8 * q2i + 5]);
      uint32_t u3 = pk2bf(sacc[m][8 * q2i + 6], sacc[m][8 * q2i + 7]);
      auto r02 = __builtin_amdgcn_permlane32_swap((int)u0, (int)u2, false, false);
      auto r13 = __builtin_amdgcn_permlane32_swap((int)u1, (int)u3, false, false);
      union { uint32_t u[4]; bf16x8 v; } pb;
      pb.u[0] = (uint32_t)r02[0]; pb.u[1] = (uint32_t)r13[0];
      pb.u[2] = (uint32_t)r02[1]; pb.u[3] = (uint32_t)r13[1];
      __builtin_amdgcn_s_setprio(1);
#pragma unroll
      for (int df = 0; df < 4; ++df) {
        int byte = (df * 32 + c) * 128 + ((t * 32 + h2 * 16) ^ ((c & 7) << 4));
        bf16x8 vf = *reinterpret_cast<const bf16x8*>(vb + byte);
        oacc[df] = __builtin_amdgcn_mfma_f32_32x32x16_bf16(vf, pb.v, oacc[df], 0, 0, 0);
      }
      __builtin_amdgcn_s_setprio(0);
    }
  };

  stage(0, 0);
#pragma unroll 1
  for (int kt = 0; kt < 31; ++kt) {
    stage((kt + 1) & 1, kt + 1);   // 8 loads/wave in flight
    VMCNT8();                      // drain tile kt's loads only
    S_BARRIER();
    compute(kt & 1);
    S_BARRIER();
  }
  VMCNT0();
  S_BARRIER();
  compute(1);

  float lrun = (l0 + l1) + (l2 + l3);
  lrun += __shfl_xor(lrun, 32, 64);
  const float inv = 1.0f / lrun;
  bf16_t* Og = O + ((size_t)(b * 2048 + qt * 128 + w * 32 + c) * 2048) + h * 128;
#pragma unroll
  for (int df = 0; df < 4; ++df)
#pragma unroll
    for (int rg = 0; rg < 4; ++rg) {
      uint32_t w0 = pk2bf(oacc[df][rg * 4 + 0] * inv, oacc[df][rg * 4 + 1] * inv);
      uint32_t w1 = pk2bf(oacc[df][rg * 4 + 2] * inv, oacc[df][rg * 4 + 3] * inv);
      uint2 ww; ww.x = w0; ww.y = w1;
      *reinterpret_cast<uint2*>(Og + df * 32 + 8 * rg + 4 * h2) = ww;
    }
}

// ---------------- host launcher ----------------
extern "C" void kernel_launch(void* const* d_in, const int* in_sizes, int n_in,
                              void* d_out, int out_size, void* d_ws, size_t ws_size,
                              hipStream_t stream)
{
  const float* x     = (const float*)d_in[0];
  const float* freqs = (const float*)d_in[2];
  const float* wqkv  = (const float*)d_in[3];
  const float* wout  = (const float*)d_in[4];
  const float* qw    = (const float*)d_in[5];
  const float* kw    = (const float*)d_in[6];
  float* out = (float*)d_out;

  bf16_t* Xb   = (bf16_t*)d_ws;           // 4096x2048
  bf16_t* Wqb  = Xb  + 8388608;           // 4096x2048
  bf16_t* Wob  = Wqb + 8388608;           // 2048x2048
  bf16_t* qkvb = Wob + 4194304;           // 4096x4096 (later aliased as O)
  bf16_t* Qdp  = qkvb + 16777216;         // [2][16][2048][128]
  bf16_t* Kdp  = Qdp + 8388608;           // [2][8][2048][128]
  bf16_t* Vtp  = Kdp + 4194304;           // [2][8][128][2048]
  bf16_t* Ob   = qkvb;                    // alias: qkv dead after preps

  (void)hipFuncSetAttribute((const void*)k_gemm256,
                            hipFuncAttributeMaxDynamicSharedMemorySize, 163840);
  (void)hipFuncSetAttribute((const void*)k_og,
                            hipFuncAttributeMaxDynamicSharedMemorySize, 98304);

  k_cvt3<<<20480, 256, 0, stream>>>(x, wqkv, wout, Xb);
  k_gemm256<<<256, 512, 163840, stream>>>(Xb, Wqb, qkvb, 4096, 4096, 2048, 1);
  k_prep<<<25088, 256, 0, stream>>>(qkvb, freqs, qw, kw, Qdp, Kdp, Vtp);
  k_attn<<<512, 256, 0, stream>>>(Qdp, Kdp, Vtp, Ob);
  k_og<<<256, 512, 98304, stream>>>(Ob, Wob, out, 4096, 2048, 2048);
}

// Round 13
// 225.727 us; speedup vs baseline: 1.1067x; 1.0371x over previous
//
#include <hip/hip_runtime.h>
#include <hip/hip_bf16.h>
#include <cstdint>

typedef __bf16 bf16_t;
typedef __attribute__((ext_vector_type(8)))  __bf16 bf16x8;
typedef __attribute__((ext_vector_type(4)))  float  f32x4;
typedef __attribute__((ext_vector_type(16))) float  f32x16;

#define AS1 __attribute__((address_space(1)))
#define AS3 __attribute__((address_space(3)))
#define DEV __device__ __forceinline__

#define S_BARRIER() asm volatile("s_barrier" ::: "memory")
#define VMCNT0()    asm volatile("s_waitcnt vmcnt(0)" ::: "memory")
#define VMCNT8()    asm volatile("s_waitcnt vmcnt(8)" ::: "memory")
#define SCHED0()    __builtin_amdgcn_sched_barrier(0)

#if __has_builtin(__builtin_amdgcn_exp2f)
#define EXP2(x) __builtin_amdgcn_exp2f(x)
#else
#define EXP2(x) exp2f(x)
#endif

DEV uint32_t pk2bf(float lo, float hi) {
  union { __bf16 h[2]; uint32_t u; } x;
  x.h[0] = (__bf16)lo; x.h[1] = (__bf16)hi; return x.u;
}

// ---------------- fused f32 -> bf16 convert (x | wqkv | wout) ----------------
__global__ __launch_bounds__(256) void k_cvt3(const float* __restrict__ s0,
                                              const float* __restrict__ s1,
                                              const float* __restrict__ s2,
                                              bf16_t* __restrict__ dst) {
  long i = (long)(blockIdx.x * 256 + threadIdx.x) * 4;
  const float* src;
  long off;
  if (i < 8388608)        { src = s0; off = i; }
  else if (i < 16777216)  { src = s1; off = i - 8388608; }
  else                    { src = s2; off = i - 16777216; }
  const float4 v = *reinterpret_cast<const float4*>(src + off);
  union { bf16_t h[4]; uint2 u; } o;
  o.h[0] = (bf16_t)v.x; o.h[1] = (bf16_t)v.y;
  o.h[2] = (bf16_t)v.z; o.h[3] = (bf16_t)v.w;
  *reinterpret_cast<uint2*>(dst + i) = o.u;
}

// ============ shared macros for the 4-phase GEMM templates ============
#define RD_A_PAIR(dst, base, MF)                                          \
  _Pragma("unroll") for (int j_ = 0; j_ < 2; ++j_)                        \
  _Pragma("unroll") for (int kk_ = 0; kk_ < 2; ++kk_) {                   \
    int p_ = (wm*128 + ((MF)+j_)*16 + c16)*128 + kk_*64 + g*16;           \
    p_ ^= ((p_>>9)&1)<<5;                                                 \
    dst[j_][kk_] = *reinterpret_cast<const bf16x8*>((const char*)(base) + p_); }

#define RD_B_ALL(dst, base)                                               \
  _Pragma("unroll") for (int i_ = 0; i_ < 4; ++i_)                        \
  _Pragma("unroll") for (int kk_ = 0; kk_ < 2; ++kk_) {                   \
    int p_ = (wn*64 + i_*16 + c16)*128 + kk_*64 + g*16;                   \
    p_ ^= ((p_>>9)&1)<<5;                                                 \
    dst[i_][kk_] = *reinterpret_cast<const bf16x8*>((const char*)(base) + p_); }

#define RD_B2(dst, base)                                                  \
  _Pragma("unroll") for (int i_ = 0; i_ < 2; ++i_)                        \
  _Pragma("unroll") for (int kk_ = 0; kk_ < 2; ++kk_) {                   \
    int p_ = (wn*32 + i_*16 + c16)*128 + kk_*64 + g*16;                   \
    p_ ^= ((p_>>9)&1)<<5;                                                 \
    dst[i_][kk_] = *reinterpret_cast<const bf16x8*>((const char*)(base) + p_); }

#define MM_PAIR(aa, MF)                                                   \
  _Pragma("unroll") for (int j_ = 0; j_ < 2; ++j_)                        \
  _Pragma("unroll") for (int i_ = 0; i_ < 4; ++i_)                        \
  _Pragma("unroll") for (int kk_ = 0; kk_ < 2; ++kk_)                     \
    acc[(MF)+j_][i_] = __builtin_amdgcn_mfma_f32_16x16x32_bf16(           \
        aa[j_][kk_], bF[i_][kk_], acc[(MF)+j_][i_], 0, 0, 0);

#define MM_PAIR2(aa, MF)                                                  \
  _Pragma("unroll") for (int j_ = 0; j_ < 2; ++j_)                        \
  _Pragma("unroll") for (int i_ = 0; i_ < 2; ++i_)                        \
  _Pragma("unroll") for (int kk_ = 0; kk_ < 2; ++kk_)                     \
    acc[(MF)+j_][i_] = __builtin_amdgcn_mfma_f32_16x16x32_bf16(           \
        aa[j_][kk_], bG[i_][kk_], acc[(MF)+j_][i_], 0, 0, 0);

#define STAGE_A(dstbase, half, tt)                                        \
  _Pragma("unroll") for (int j_ = 0; j_ < 2; ++j_)                        \
    __builtin_amdgcn_global_load_lds(                                     \
        (const AS1 void*)(Ag + srcA[half][j_] + (tt)*64),                 \
        (AS3 void*)((char*)(dstbase) + ((half)*1024 + 512*j_ + wuni)*16), \
        16, 0, 0);

#define STAGE_B(dstbase, half, tt)                                        \
  _Pragma("unroll") for (int j_ = 0; j_ < 2; ++j_)                        \
    __builtin_amdgcn_global_load_lds(                                     \
        (const AS1 void*)(Bg + srcB[half][j_] + (tt)*64),                 \
        (AS3 void*)((char*)(dstbase) + ((half)*1024 + 512*j_ + wuni)*16), \
        16, 0, 0);

#define STAGE_B2(dstbase, tt)                                             \
  _Pragma("unroll") for (int j_ = 0; j_ < 2; ++j_)                        \
    __builtin_amdgcn_global_load_lds(                                     \
        (const AS1 void*)(Bg + srcB2[j_] + (tt)*64),                      \
        (AS3 void*)((char*)(dstbase) + (512*j_ + wuni)*16), 16, 0, 0);

// ================= 256x256 4-phase GEMM (QKV projection) =================
__global__ __launch_bounds__(512, 2) void k_gemm256(
    const bf16_t* __restrict__ Ag, const bf16_t* __restrict__ Bg,
    void* __restrict__ Cv, int M, int N, int K, int out_bf16)
{
  extern __shared__ char smemraw[];
  const int tid = threadIdx.x;
  const int w = tid >> 6, l = tid & 63;
  const int wm = w >> 2, wn = w & 3;
  const int c16 = l & 15, g = l >> 4;
  const int wuni = tid & 0x1C0;          // w*64, wave-uniform

  const int nwg = gridDim.x, cpx = nwg >> 3;
  const int bid = blockIdx.x;
  const int L = (bid & 7) * cpx + (bid >> 3);
  const int nbx = N >> 8;
  const int m0 = (L / nbx) * 256, n0 = (L % nbx) * 256;

  int srcA[2][2], srcB[2][2];
#pragma unroll
  for (int half = 0; half < 2; ++half)
#pragma unroll
    for (int j = 0; j < 2; ++j) {
      int ch = half * 1024 + 512 * j + tid;
      int cc = ch ^ (((ch >> 5) & 1) << 1);
      int row = cc >> 3, c8 = (cc & 7) * 8;
      srcA[half][j] = (m0 + row) * K + c8;
      srcB[half][j] = (n0 + row) * K + c8;
    }

  f32x4 acc[8][4] = {};
  bf16x8 aA[2][2], aB[2][2], bF[4][2];

  char* const Ab0 = smemraw;
  char* const Ab1 = smemraw + 32768;
  char* const Bb0 = smemraw + 65536;
  char* const Bb1 = smemraw + 98304;

  const int NT = K >> 6;

  STAGE_A(Ab0, 0, 0); STAGE_A(Ab0, 1, 0);
  STAGE_B(Bb0, 0, 0); STAGE_B(Bb0, 1, 0);
  VMCNT0();
  S_BARRIER();
  RD_A_PAIR(aA, Ab0, 0);
  RD_B_ALL(bF, Bb0);

#pragma unroll 1
  for (int t = 0; t < NT; ++t) {
    char* const Asp = (t & 1) ? Ab1 : Ab0;
    char* const Asn = (t & 1) ? Ab0 : Ab1;
    char* const Bsn = (t & 1) ? Bb0 : Bb1;
    const bool more = (t + 1 < NT);

    RD_A_PAIR(aB, Asp, 2);
    if (more) { STAGE_A(Asn, 0, t + 1); STAGE_A(Asn, 1, t + 1); }
    S_BARRIER();
    __builtin_amdgcn_s_setprio(1);
    MM_PAIR(aA, 0);
    __builtin_amdgcn_s_setprio(0); SCHED0();
    S_BARRIER();

    RD_A_PAIR(aA, Asp, 4);
    if (more) { STAGE_B(Bsn, 0, t + 1); STAGE_B(Bsn, 1, t + 1); }
    S_BARRIER();
    __builtin_amdgcn_s_setprio(1);
    MM_PAIR(aB, 2);
    __builtin_amdgcn_s_setprio(0); SCHED0();
    S_BARRIER();

    RD_A_PAIR(aB, Asp, 6);
    S_BARRIER();
    __builtin_amdgcn_s_setprio(1);
    MM_PAIR(aA, 4);
    __builtin_amdgcn_s_setprio(0); SCHED0();
    S_BARRIER();

    if (more) { VMCNT0(); }
    S_BARRIER();
    __builtin_amdgcn_s_setprio(1);
    MM_PAIR(aB, 6);
    __builtin_amdgcn_s_setprio(0); SCHED0();
    if (more) { RD_A_PAIR(aA, Asn, 0); RD_B_ALL(bF, Bsn); }
    S_BARRIER();
  }

#pragma unroll
  for (int mf = 0; mf < 8; ++mf)
#pragma unroll
    for (int nf = 0; nf < 4; ++nf) {
      const int cc = n0 + wn * 64 + nf * 16 + c16;
#pragma unroll
      for (int r = 0; r < 4; ++r) {
        const int rr = m0 + wm * 128 + mf * 16 + g * 4 + r;
        if (out_bf16)
          ((bf16_t*)Cv)[(size_t)rr * N + cc] = (bf16_t)acc[mf][nf][r];
        else
          ((float*)Cv)[(size_t)rr * N + cc] = acc[mf][nf][r];
      }
    }
}

// ================= 256x128 4-phase GEMM (out projection, f32 out) =================
__global__ __launch_bounds__(512, 2) void k_og(
    const bf16_t* __restrict__ Ag, const bf16_t* __restrict__ Bg,
    float* __restrict__ Cv, int M, int N, int K)
{
  extern __shared__ char smemraw[];
  const int tid = threadIdx.x;
  const int w = tid >> 6, l = tid & 63;
  const int wm = w >> 2, wn = w & 3;
  const int c16 = l & 15, g = l >> 4;
  const int wuni = tid & 0x1C0;

  const int nwg = gridDim.x, cpx = nwg >> 3;
  const int bid = blockIdx.x;
  const int L = (bid & 7) * cpx + (bid >> 3);
  const int nbx = N >> 7;
  const int m0 = (L / nbx) * 256, n0 = (L % nbx) * 128;

  int srcA[2][2], srcB2[2];
#pragma unroll
  for (int half = 0; half < 2; ++half)
#pragma unroll
    for (int j = 0; j < 2; ++j) {
      int ch = half * 1024 + 512 * j + tid;
      int cc = ch ^ (((ch >> 5) & 1) << 1);
      int row = cc >> 3, c8 = (cc & 7) * 8;
      srcA[half][j] = (m0 + row) * K + c8;
    }
#pragma unroll
  for (int j = 0; j < 2; ++j) {
    int ch = 512 * j + tid;
    int cc = ch ^ (((ch >> 5) & 1) << 1);
    int row = cc >> 3, c8 = (cc & 7) * 8;
    srcB2[j] = (n0 + row) * K + c8;
  }

  f32x4 acc[8][2] = {};
  bf16x8 aA[2][2], aB[2][2], bG[2][2];

  char* const Ab0 = smemraw;
  char* const Ab1 = smemraw + 32768;
  char* const Bb0 = smemraw + 65536;
  char* const Bb1 = smemraw + 81920;

  const int NT = K >> 6;

  STAGE_A(Ab0, 0, 0); STAGE_A(Ab0, 1, 0);
  STAGE_B2(Bb0, 0);
  VMCNT0();
  S_BARRIER();
  RD_A_PAIR(aA, Ab0, 0);
  RD_B2(bG, Bb0);

#pragma unroll 1
  for (int t = 0; t < NT; ++t) {
    char* const Asp = (t & 1) ? Ab1 : Ab0;
    char* const Asn = (t & 1) ? Ab0 : Ab1;
    char* const Bsn = (t & 1) ? Bb0 : Bb1;
    const bool more = (t + 1 < NT);

    RD_A_PAIR(aB, Asp, 2);
    if (more) { STAGE_A(Asn, 0, t + 1); STAGE_A(Asn, 1, t + 1); }
    S_BARRIER();
    __builtin_amdgcn_s_setprio(1);
    MM_PAIR2(aA, 0);
    __builtin_amdgcn_s_setprio(0); SCHED0();
    S_BARRIER();

    RD_A_PAIR(aA, Asp, 4);
    if (more) { STAGE_B2(Bsn, t + 1); }
    S_BARRIER();
    __builtin_amdgcn_s_setprio(1);
    MM_PAIR2(aB, 2);
    __builtin_amdgcn_s_setprio(0); SCHED0();
    S_BARRIER();

    RD_A_PAIR(aB, Asp, 6);
    S_BARRIER();
    __builtin_amdgcn_s_setprio(1);
    MM_PAIR2(aA, 4);
    __builtin_amdgcn_s_setprio(0); SCHED0();
    S_BARRIER();

    if (more) { VMCNT0(); }
    S_BARRIER();
    __builtin_amdgcn_s_setprio(1);
    MM_PAIR2(aB, 6);
    __builtin_amdgcn_s_setprio(0); SCHED0();
    if (more) { RD_A_PAIR(aA, Asn, 0); RD_B2(bG, Bsn); }
    S_BARRIER();
  }

#pragma unroll
  for (int mf = 0; mf < 8; ++mf)
#pragma unroll
    for (int nf = 0; nf < 2; ++nf) {
      const int cc = n0 + wn * 32 + nf * 16 + c16;
#pragma unroll
      for (int r = 0; r < 4; ++r) {
        const int rr = m0 + wm * 128 + mf * 16 + g * 4 + r;
        Cv[(size_t)rr * N + cc] = acc[mf][nf][r];
      }
    }
}

// ------- merged prep: RMSNorm+RoPE for Q/K (vectorized 16B/lane) | V transpose -------
// Q/K branch: 16 lanes per 128-d row (bf16x8 load), 4 rows/wave, 16 rows/block.
// Row-sum via 4-step shfl_xor within the 16-lane group; RoPE pairs are in-lane.
__global__ __launch_bounds__(256) void k_prep(
    const bf16_t* __restrict__ qkv, const float* __restrict__ freqs,
    const float* __restrict__ qw, const float* __restrict__ kw,
    bf16_t* __restrict__ Qd, bf16_t* __restrict__ Kd,
    bf16_t* __restrict__ Vt)
{
  __shared__ bf16_t vt[64][136];
  const int bid = blockIdx.x;
  if (bid < 6144) {
    const int wv = threadIdx.x >> 6, l = threadIdx.x & 63;
    const int gi = l >> 4, k = l & 15;
    const int R = bid * 16 + wv * 4 + gi;      // [0, 98304)
    const int j = R >> 12;                     // 0..23
    const int token = R & 4095;
    const int s = token & 2047, b = token >> 11;
    const bool isq = (j < 16);
    const int col0 = isq ? (j << 7) : (2048 + ((j - 16) << 7));

    const bf16x8 x8 = *reinterpret_cast<const bf16x8*>(
        qkv + (size_t)token * 4096 + col0 + k * 8);
    float xf[8];
    float ss = 0.0f;
#pragma unroll
    for (int e = 0; e < 8; ++e) { xf[e] = (float)x8[e]; ss += xf[e] * xf[e]; }
    ss += __shfl_xor(ss, 1, 64);
    ss += __shfl_xor(ss, 2, 64);
    ss += __shfl_xor(ss, 4, 64);
    ss += __shfl_xor(ss, 8, 64);
    const float rn = rsqrtf(ss * (1.0f / 128.0f) + 1.1920929e-7f);

    const float* wp = (isq ? qw : kw) + k * 8;
    const float4 w0 = *reinterpret_cast<const float4*>(wp);
    const float4 w1 = *reinterpret_cast<const float4*>(wp + 4);
    const float wv8[8] = { w0.x, w0.y, w0.z, w0.w, w1.x, w1.y, w1.z, w1.w };
    const float qs = isq ? 0.1275187989014331f : 1.0f;   // HD^-0.5 * log2(e)

    union { bf16_t h[8]; uint4 u; } out;
    const float* fbase = freqs + (size_t)s * 256 + k * 16;
#pragma unroll
    for (int p = 0; p < 4; ++p) {
      const float4 f = *reinterpret_cast<const float4*>(fbase + p * 4);
      const float y0 = xf[2 * p] * rn * wv8[2 * p];
      const float y1 = xf[2 * p + 1] * rn * wv8[2 * p + 1];
      out.h[2 * p]     = (bf16_t)((f.x * y0 + f.y * y1) * qs);
      out.h[2 * p + 1] = (bf16_t)((f.z * y0 + f.w * y1) * qs);
    }
    bf16_t* dst = isq
        ? Qd + ((size_t)(b * 16 + j) * 2048 + s) * 128 + k * 8
        : Kd + ((size_t)(b * 8 + (j - 16)) * 2048 + s) * 128 + k * 8;
    *reinterpret_cast<uint4*>(dst) = out.u;
  } else {
    const int vb = bid - 6144;       // 512 = 2*8*32
    const int tid = threadIdx.x;
    const int st = vb & 31, kh = (vb >> 5) & 7, b = vb >> 8;
    const int s0 = st * 64;
#pragma unroll
    for (int i = 0; i < 4; ++i) {
      int ch = tid + 256 * i;
      int srow = ch >> 4, d8 = ch & 15;
      bf16x8 v = *reinterpret_cast<const bf16x8*>(
          qkv + (size_t)(b * 2048 + s0 + srow) * 4096 + 3072 + kh * 128 + d8 * 8);
      *reinterpret_cast<bf16x8*>(&vt[srow][d8 * 8]) = v;
    }
    __syncthreads();
    const int d = tid >> 1, sc = tid & 1;
    bf16_t* dst = Vt + ((size_t)(b * 8 + kh) * 128 + d) * 2048 + s0 + 32 * sc;
#pragma unroll
    for (int grp = 0; grp < 4; ++grp) {
      uint32_t pk[4];
#pragma unroll
      for (int q = 0; q < 4; ++q) {
        int jj = 32 * sc + grp * 8 + q * 2;
        union { __bf16 h[2]; uint32_t u; } e;
        e.h[0] = vt[jj][d]; e.h[1] = vt[jj + 1][d];
        pk[q] = e.u;
      }
      uint4 o; o.x = pk[0]; o.y = pk[1]; o.z = pk[2]; o.w = pk[3];
      *reinterpret_cast<uint4*>(dst + grp * 8) = o;
    }
  }
}

// ---------------- Flash attention (R7-proven: staged LDS, counted vmcnt) ----------------
__global__ __launch_bounds__(256, 2) void k_attn(
    const bf16_t* __restrict__ Qd, const bf16_t* __restrict__ Kd,
    const bf16_t* __restrict__ Vt, bf16_t* __restrict__ O)
{
  __shared__ bf16_t kbuf[2][64 * 128];   // [key][d], XOR-swizzled
  __shared__ bf16_t vbuf[2][128 * 64];   // [d][key], XOR-swizzled
  const int tid = threadIdx.x;
  const int w = tid >> 6, l = tid & 63;
  const int c = l & 31, h2 = l >> 5;
  const int bid = blockIdx.x;            // 512 = 2*16*16
  const int qt = bid & 15, h = (bid >> 4) & 15, b = bid >> 8;
  const int kvh = h >> 1;                // NREP=2
  const bf16_t* Qg = Qd + ((size_t)(b * 16 + h) * 2048 + qt * 128 + w * 32) * 128;
  const bf16_t* Kg = Kd + ((size_t)(b * 8 + kvh) * 2048) * 128;
  const bf16_t* Vg = Vt + ((size_t)(b * 8 + kvh) * 128) * 2048;

  bf16x8 qf[8];
#pragma unroll
  for (int s = 0; s < 8; ++s)
    qf[s] = *reinterpret_cast<const bf16x8*>(Qg + (size_t)c * 128 + s * 16 + h2 * 8);

  f32x16 oacc[4] = {};
  float l0 = 0.f, l1 = 0.f, l2 = 0.f, l3 = 0.f;

  auto stage = [&](int buf, int kt) {
#pragma unroll
    for (int i = 0; i < 4; ++i) {
      int ch = tid + 256 * i;
      { // K tile: LDS linear, source pre-swizzled (byte ^= (key&7)<<4)
        int key = ch >> 4, d16 = ch & 15;
        int soff = key * 256 + ((d16 * 16) ^ ((key & 7) << 4));
        __builtin_amdgcn_global_load_lds(
            (const AS1 void*)((const char*)Kg + (size_t)kt * 64 * 256 + soff),
            (AS3 void*)((char*)&kbuf[buf][0] + (w * 64 + 256 * i) * 16), 16, 0, 0);
      }
      { // Vt tile: source pre-swizzled (k-chunk ^= d&7)
        int d = ch >> 3, k8 = (ch & 7) ^ (d & 7);
        __builtin_amdgcn_global_load_lds(
            (const AS1 void*)(Vg + (size_t)d * 2048 + kt * 64 + k8 * 8),
            (AS3 void*)((char*)&vbuf[buf][0] + (w * 64 + 256 * i) * 16), 16, 0, 0);
      }
    }
  };

  auto compute = [&](int buf) {
    f32x16 sacc[2] = {};
    const char* kb = (const char*)&kbuf[buf][0];
    __builtin_amdgcn_s_setprio(1);
#pragma unroll
    for (int m = 0; m < 2; ++m)
#pragma unroll
      for (int s = 0; s < 8; ++s) {
        int byte = (m * 32 + c) * 256 + ((s * 32 + h2 * 16) ^ ((c & 7) << 4));
        bf16x8 kf = *reinterpret_cast<const bf16x8*>(kb + byte);
        sacc[m] = __builtin_amdgcn_mfma_f32_32x32x16_bf16(kf, qf[s], sacc[m], 0, 0, 0);
      }
    __builtin_amdgcn_s_setprio(0);

#pragma unroll
    for (int m = 0; m < 2; ++m)
#pragma unroll
      for (int r = 0; r < 16; r += 4) {
        float p0 = EXP2(sacc[m][r + 0]);
        float p1 = EXP2(sacc[m][r + 1]);
        float p2 = EXP2(sacc[m][r + 2]);
        float p3 = EXP2(sacc[m][r + 3]);
        sacc[m][r + 0] = p0; sacc[m][r + 1] = p1;
        sacc[m][r + 2] = p2; sacc[m][r + 3] = p3;
        l0 += p0; l1 += p1; l2 += p2; l3 += p3;
      }

    const char* vb = (const char*)&vbuf[buf][0];
#pragma unroll
    for (int t = 0; t < 4; ++t) {
      const int m = t >> 1, q2i = t & 1;
      uint32_t u0 = pk2bf(sacc[m][8 * q2i + 0], sacc[m][8 * q2i + 1]);
      uint32_t u1 = pk2bf(sacc[m][8 * q2i + 2], sacc[m][8 * q2i + 3]);
      uint32_t u2 = pk2bf(sacc[m][8 * q2i + 4], sacc[m][8 * q2i + 5]);
      uint32_t u3 = pk2bf(sacc[m][8 * q2i + 6], sacc[m][8 * q2i + 7]);
      auto r02 = __builtin_amdgcn_permlane32_swap((int)u0, (int)u2, false, false);
      auto r13 = __builtin_amdgcn_permlane32_swap((int)u1, (int)u3, false, false);
      union { uint32_t u[4]; bf16x8 v; } pb;
      pb.u[0] = (uint32_t)r02[0]; pb.u[1] = (uint32_t)r13[0];
      pb.u[2] = (uint32_t)r02[1]; pb.u[3] = (uint32_t)r13[1];
      __builtin_amdgcn_s_setprio(1);
#pragma unroll
      for (int df = 0; df < 4; ++df) {
        int byte = (df * 32 + c) * 128 + ((t * 32 + h2 * 16) ^ ((c & 7) << 4));
        bf16x8 vf = *reinterpret_cast<const bf16x8*>(vb + byte);
        oacc[df] = __builtin_amdgcn_mfma_f32_32x32x16_bf16(vf, pb.v, oacc[df], 0, 0, 0);
      }
      __builtin_amdgcn_s_setprio(0);
    }
  };

  stage(0, 0);
#pragma unroll 1
  for (int kt = 0; kt < 31; ++kt) {
    stage((kt + 1) & 1, kt + 1);   // 8 loads/wave in flight
    VMCNT8();                      // drain tile kt's loads only
    S_BARRIER();
    compute(kt & 1);
    S_BARRIER();
  }
  VMCNT0();
  S_BARRIER();
  compute(1);

  float lrun = (l0 + l1) + (l2 + l3);
  lrun += __shfl_xor(lrun, 32, 64);
  const float inv = 1.0f / lrun;
  bf16_t* Og = O + ((size_t)(b * 2048 + qt * 128 + w * 32 + c) * 2048) + h * 128;
#pragma unroll
  for (int df = 0; df < 4; ++df)
#pragma unroll
    for (int rg = 0; rg < 4; ++rg) {
      uint32_t w0 = pk2bf(oacc[df][rg * 4 + 0] * inv, oacc[df][rg * 4 + 1] * inv);
      uint32_t w1 = pk2bf(oacc[df][rg * 4 + 2] * inv, oacc[df][rg * 4 + 3] * inv);
      uint2 ww; ww.x = w0; ww.y = w1;
      *reinterpret_cast<uint2*>(Og + df * 32 + 8 * rg + 4 * h2) = ww;
    }
}

// ---------------- host launcher ----------------
extern "C" void kernel_launch(void* const* d_in, const int* in_sizes, int n_in,
                              void* d_out, int out_size, void* d_ws, size_t ws_size,
                              hipStream_t stream)
{
  const float* x     = (const float*)d_in[0];
  const float* freqs = (const float*)d_in[2];
  const float* wqkv  = (const float*)d_in[3];
  const float* wout  = (const float*)d_in[4];
  const float* qw    = (const float*)d_in[5];
  const float* kw    = (const float*)d_in[6];
  float* out = (float*)d_out;

  bf16_t* Xb   = (bf16_t*)d_ws;           // 4096x2048
  bf16_t* Wqb  = Xb  + 8388608;           // 4096x2048
  bf16_t* Wob  = Wqb + 8388608;           // 2048x2048
  bf16_t* qkvb = Wob + 4194304;           // 4096x4096 (later aliased as O)
  bf16_t* Qdp  = qkvb + 16777216;         // [2][16][2048][128]
  bf16_t* Kdp  = Qdp + 8388608;           // [2][8][2048][128]
  bf16_t* Vtp  = Kdp + 4194304;           // [2][8][128][2048]
  bf16_t* Ob   = qkvb;                    // alias: qkv dead after preps

  (void)hipFuncSetAttribute((const void*)k_gemm256,
                            hipFuncAttributeMaxDynamicSharedMemorySize, 131072);
  (void)hipFuncSetAttribute((const void*)k_og,
                            hipFuncAttributeMaxDynamicSharedMemorySize, 98304);

  k_cvt3<<<20480, 256, 0, stream>>>(x, wqkv, wout, Xb);
  k_gemm256<<<256, 512, 131072, stream>>>(Xb, Wqb, qkvb, 4096, 4096, 2048, 1);
  k_prep<<<6656, 256, 0, stream>>>(qkvb, freqs, qw, kw, Qdp, Kdp, Vtp);
  k_attn<<<512, 256, 0, stream>>>(Qdp, Kdp, Vtp, Ob);
  k_og<<<256, 512, 98304, stream>>>(Ob, Wob, out, 4096, 2048, 2048);
}